// Round 7
// baseline (8789.321 us; speedup 1.0000x reference)
//
#include <hip/hip_runtime.h>
#include <math.h>

#define DD 64
#define SCAN_TPB 256
#define SCAN_EPT 8
#define SCAN_EPB (SCAN_TPB * SCAN_EPT)  // 2048 elements per block

// ============================ CSR build kernels ============================
// Two-pass bucketed build: pass A appends edges into ~<=1024 coarse buckets
// (dense writes, no line amplification); per-target hist + pass B then operate
// with bucket locality (hot cursor window <= 4KB, write window ~40KB in L2).

__global__ void bucket_hist_kernel(int* __restrict__ bcnt, const int* __restrict__ tgt,
                                   int E, int shift) {
    int g = blockIdx.x * blockDim.x + threadIdx.x;
    int stride = gridDim.x * blockDim.x;
    for (int e = g; e < E; e += stride) atomicAdd(&bcnt[tgt[e] >> shift], 1);
}

// single block: bcur = exclusive scan of bcnt (nb <= 1024)
__global__ void bucket_scan_kernel(int* __restrict__ bcur, const int* __restrict__ bcnt,
                                   int nb) {
    __shared__ int sh[1024];
    int t = threadIdx.x;
    int v = (t < nb) ? bcnt[t] : 0;
    sh[t] = v;
    __syncthreads();
    for (int o = 1; o < 1024; o <<= 1) {
        int x = (t >= o) ? sh[t - o] : 0;
        __syncthreads();
        sh[t] += x;
        __syncthreads();
    }
    if (t < nb) bcur[t] = sh[t] - v;
}

// pass A: append {tgt, src, val} into bucket-ordered staging (dense writes)
__global__ void passA_kernel(int* __restrict__ stgT, int* __restrict__ stgS,
                             float* __restrict__ stgV, int* __restrict__ bcur,
                             const int* __restrict__ tgt, const int* __restrict__ src,
                             const float* __restrict__ val, int E, int shift) {
    int g = blockIdx.x * blockDim.x + threadIdx.x;
    int stride = gridDim.x * blockDim.x;
    for (int e = g; e < E; e += stride) {
        int t_ = tgt[e];
        int p = atomicAdd(&bcur[t_ >> shift], 1);
        stgT[p] = t_;
        stgS[p] = src[e];
        stgV[p] = val[e];
    }
}

__global__ void hist_kernel(int* __restrict__ cnt, const int* __restrict__ tgt, int E) {
    int g = blockIdx.x * blockDim.x + threadIdx.x;
    int stride = gridDim.x * blockDim.x;
    for (int e = g; e < E; e += stride) atomicAdd(&cnt[tgt[e]], 1);
}

__global__ void scan_pass1(int* __restrict__ blocksum, const int* __restrict__ cnt, int n) {
    int base = blockIdx.x * SCAN_EPB + threadIdx.x * SCAN_EPT;
    int s = 0;
#pragma unroll
    for (int k = 0; k < SCAN_EPT; ++k) {
        int i = base + k;
        if (i < n) s += cnt[i];
    }
#pragma unroll
    for (int o = 32; o >= 1; o >>= 1) s += __shfl_xor(s, o);
    __shared__ int ws_[4];
    if ((threadIdx.x & 63) == 0) ws_[threadIdx.x >> 6] = s;
    __syncthreads();
    if (threadIdx.x == 0) blocksum[blockIdx.x] = ws_[0] + ws_[1] + ws_[2] + ws_[3];
}

__global__ void scan_pass2(int* __restrict__ blocksum, int nb, int* __restrict__ ptr_n) {
    __shared__ int sh[1024];
    int t = threadIdx.x;
    int v = (t < nb) ? blocksum[t] : 0;
    sh[t] = v;
    __syncthreads();
    for (int o = 1; o < 1024; o <<= 1) {
        int x = (t >= o) ? sh[t - o] : 0;
        __syncthreads();
        sh[t] += x;
        __syncthreads();
    }
    if (t < nb) blocksum[t] = sh[t] - v;  // exclusive
    if (t == nb - 1) ptr_n[0] = sh[t];
}

// ptr[i] = cursor[i] = blockoff + intra-block exclusive scan (cursor may alias cnt)
__global__ void scan_pass3(int* __restrict__ ptr, int* __restrict__ cursor,
                           const int* __restrict__ cnt, const int* __restrict__ blockoff,
                           int n) {
    int base = blockIdx.x * SCAN_EPB + threadIdx.x * SCAN_EPT;
    int vals[SCAN_EPT];
    int s = 0;
#pragma unroll
    for (int k = 0; k < SCAN_EPT; ++k) {
        int i = base + k;
        int c = (i < n) ? cnt[i] : 0;
        vals[k] = s;
        s += c;
    }
    int incl = s;
#pragma unroll
    for (int o = 1; o < 64; o <<= 1) {
        int x = __shfl_up(incl, o);
        if ((threadIdx.x & 63) >= o) incl += x;
    }
    __shared__ int wtot[4];
    if ((threadIdx.x & 63) == 63) wtot[threadIdx.x >> 6] = incl;
    __syncthreads();
    int woff = 0;
    int wv = threadIdx.x >> 6;
    for (int k = 0; k < 4; ++k)
        if (k < wv) woff += wtot[k];
    int texcl = incl - s + woff + blockoff[blockIdx.x];
#pragma unroll
    for (int k = 0; k < SCAN_EPT; ++k) {
        int i = base + k;
        if (i < n) {
            int p = texcl + vals[k];
            ptr[i] = p;
            cursor[i] = p;
        }
    }
}

// pass B: staged (bucket-ordered) -> final pairs; cursor/write windows are L2-local
__global__ void passB_kernel(int2* __restrict__ pairs, int* __restrict__ cursor,
                             const int* __restrict__ stgT, const int* __restrict__ stgS,
                             const float* __restrict__ stgV, int E) {
    int g = blockIdx.x * blockDim.x + threadIdx.x;
    int stride = gridDim.x * blockDim.x;
    for (int e = g; e < E; e += stride) {
        int t_ = stgT[e];
        int2 pr;
        pr.x = stgS[e];
        pr.y = __float_as_int(stgV[e]);
        int p = atomicAdd(&cursor[t_], 1);
        pairs[p] = pr;
    }
}

// ======================= gather-based segmented SpMM =======================
// one wave per output row; lane = dim.
//   acc  = sum_e val_e * in [src_e];   acc2 = sum_e val_e * in2[src_e]
//   out [r] = (acc  + add1[r] + add2[r]) * scale1        (add2 may alias out)
//   out2[r] = (acc2 + f*acc  + addB[r]) * scale2         (dual only)
__global__ void spmm_csr_kernel(float* __restrict__ out, const float* __restrict__ in,
                                const int2* __restrict__ pairs, const int* __restrict__ ptr,
                                int nrows,
                                const float* __restrict__ add1, const float* __restrict__ add2,
                                float scale1,
                                const float* __restrict__ in2, float* __restrict__ out2,
                                const float* __restrict__ addB, float f, float scale2) {
    int w = (int)(((unsigned)blockIdx.x * blockDim.x + threadIdx.x) >> 6);
    int lane = threadIdx.x & 63;
    if (w >= nrows) return;
    int p = ptr[w];
    int end = ptr[w + 1];
    size_t rowoff = (size_t)w * DD + lane;
    float acc = 0.f, acc2 = 0.f;
    const bool dual = (in2 != nullptr);
    for (; p + 8 <= end; p += 8) {
        int ss[8];
        float vv[8];
#pragma unroll
        for (int k = 0; k < 8; ++k) {
            int2 pr = pairs[p + k];
            ss[k] = __builtin_amdgcn_readfirstlane(pr.x);
            vv[k] = __int_as_float(__builtin_amdgcn_readfirstlane(pr.y));
        }
#pragma unroll
        for (int k = 0; k < 8; ++k) acc += vv[k] * in[(size_t)ss[k] * DD + lane];
        if (dual) {
#pragma unroll
            for (int k = 0; k < 8; ++k) acc2 += vv[k] * in2[(size_t)ss[k] * DD + lane];
        }
    }
    for (; p < end; ++p) {
        int2 pr = pairs[p];
        int s = __builtin_amdgcn_readfirstlane(pr.x);
        float v = __int_as_float(__builtin_amdgcn_readfirstlane(pr.y));
        acc += v * in[(size_t)s * DD + lane];
        if (dual) acc2 += v * in2[(size_t)s * DD + lane];
    }
    float r = acc;
    if (add1) r += add1[rowoff];
    if (add2) r += add2[rowoff];
    out[rowoff] = r * scale1;
    if (dual) {
        float r2 = acc2 + f * acc;
        if (addB) r2 += addB[rowoff];
        out2[rowoff] = r2 * scale2;
    }
}

// ============================= dense helpers ==============================

__global__ void gather_rows_kernel(float* __restrict__ raw, const float* __restrict__ src,
                                   const int* __restrict__ idx, int nrows, int istride) {
    int g = blockIdx.x * blockDim.x + threadIdx.x;
    if (g >= nrows * DD) return;
    int r = g >> 6;
    raw[g] = src[(size_t)idx[(size_t)r * istride] * DD + (g & 63)];
}

__global__ void gather_rows_norm_kernel(float* __restrict__ raw, float* __restrict__ nrm,
                                        const float* __restrict__ src,
                                        const int* __restrict__ idx, int nrows, int istride) {
    int r = blockIdx.x;
    if (r >= nrows) return;
    int d = threadIdx.x;
    float v = src[(size_t)idx[(size_t)r * istride] * DD + d];
    if (raw) raw[(size_t)r * DD + d] = v;
    float ss = v * v;
#pragma unroll
    for (int o = 32; o >= 1; o >>= 1) ss += __shfl_xor(ss, o);
    nrm[(size_t)r * DD + d] = v * rsqrtf(ss + 1e-8f);
}

// out[64][n] = in[n][64]^T
__global__ void transpose64_kernel(float* __restrict__ out, const float* __restrict__ in,
                                   int n) {
    __shared__ float T[64][65];
    int b0 = blockIdx.x * 64;
    int t = threadIdx.x;
#pragma unroll
    for (int k = 0; k < 4; ++k) {
        int f = k * 1024 + t * 4;
        int r = f >> 6, c = f & 63;
        float4 v = *(const float4*)(in + (size_t)(b0 + r) * 64 + c);
        T[r][c] = v.x; T[r][c + 1] = v.y; T[r][c + 2] = v.z; T[r][c + 3] = v.w;
    }
    __syncthreads();
#pragma unroll
    for (int k = 0; k < 4; ++k) {
        int f = k * 1024 + t * 4;
        int d = f >> 6, c = f & 63;
        float4 v;
        v.x = T[c][d]; v.y = T[c + 1][d]; v.z = T[c + 2][d]; v.w = T[c + 3][d];
        *(float4*)(out + (size_t)d * n + b0 + c) = v;
    }
}

__global__ void batch_pred_kernel(const float* __restrict__ u1b, const float* __restrict__ u2b,
                                  const float* __restrict__ u3b,
                                  const float* __restrict__ b1b, const float* __restrict__ b2b,
                                  const float* __restrict__ b3b,
                                  const float* __restrict__ W1, const float* __restrict__ c1,
                                  const float* __restrict__ W2, const float* __restrict__ c2,
                                  const float* __restrict__ W3, const float* __restrict__ c3,
                                  float* __restrict__ acc, int nb) {
    int b = blockIdx.x;
    if (b >= nb) return;
    int d = threadIdx.x;
    float ud1 = u1b[(size_t)b * DD + d];
    float ud2 = u2b[(size_t)b * DD + d];
    float ud3 = u3b[(size_t)b * DD + d];
    float pred[2];
#pragma unroll
    for (int p = 0; p < 2; ++p) {
        size_t r = (size_t)(b * 2 + p) * DD + d;
        float s0 = ud1 * b1b[r];
        float s1 = ud2 * b2b[r];
        float s2 = ud3 * b3b[r];
#pragma unroll
        for (int o = 32; o >= 1; o >>= 1) {
            s0 += __shfl_xor(s0, o);
            s1 += __shfl_xor(s1, o);
            s2 += __shfl_xor(s2, o);
        }
        float t0 = tanhf(s0 * W1[0] + s1 * W1[1] + s2 * W1[2] + c1[0]);
        float t1 = tanhf(s0 * W1[3] + s1 * W1[4] + s2 * W1[5] + c1[1]);
        float t2 = tanhf(s0 * W1[6] + s1 * W1[7] + s2 * W1[8] + c1[2]);
        float g0 = tanhf(t0 * W2[0] + t1 * W2[1] + t2 * W2[2] + c2[0]);
        float g1 = tanhf(t0 * W2[3] + t1 * W2[4] + t2 * W2[5] + c2[1]);
        float g2 = tanhf(t0 * W2[6] + t1 * W2[7] + t2 * W2[8] + c2[2]);
        pred[p] = g0 * W3[0] + g1 * W3[1] + g2 * W3[2] + c3[0];
    }
    if (d == 0) {
        float x = pred[1] - pred[0];
        float sp = (x > 20.0f) ? x : log1pf(expf(x));
        unsafeAtomicAdd(acc, sp);
    }
}

// partial online-LSE: block = 1 row, wave wv handles column quarter wv.
// Bt d-major [64][n], float4 per lane (coalesced 1KB wave loads).
__global__ void nce_part_kernel(const float* __restrict__ A, const float* __restrict__ Bt,
                                float* __restrict__ pm, float* __restrict__ ps,
                                float* __restrict__ pd, int n, float invtemp) {
    int wv = threadIdx.x >> 6;
    int lane = threadIdx.x & 63;
    int row = blockIdx.x;
    float4 a4[16];
    const float4* Ap = (const float4*)(A + (size_t)row * DD);
#pragma unroll
    for (int q = 0; q < 16; ++q) a4[q] = Ap[q];
    int quarter = n >> 2;
    int c0 = wv * quarter;
    float m = -1e30f, ssum = 0.0f, diag = 0.0f;
    int ntile = quarter >> 8;  // tiles of 256 cols
    for (int t = 0; t < ntile; ++t) {
        int j0 = c0 + (t << 8) + (lane << 2);
        float dx = 0.f, dy = 0.f, dz = 0.f, dw = 0.f;
#pragma unroll
        for (int q = 0; q < 16; ++q) {
            float4 a = a4[q];
            float4 r0 = *(const float4*)(Bt + (size_t)(4 * q + 0) * n + j0);
            float4 r1 = *(const float4*)(Bt + (size_t)(4 * q + 1) * n + j0);
            float4 r2 = *(const float4*)(Bt + (size_t)(4 * q + 2) * n + j0);
            float4 r3 = *(const float4*)(Bt + (size_t)(4 * q + 3) * n + j0);
            dx += a.x * r0.x + a.y * r1.x + a.z * r2.x + a.w * r3.x;
            dy += a.x * r0.y + a.y * r1.y + a.z * r2.y + a.w * r3.y;
            dz += a.x * r0.z + a.y * r1.z + a.z * r2.z + a.w * r3.z;
            dw += a.x * r0.w + a.y * r1.w + a.z * r2.w + a.w * r3.w;
        }
        float lg[4] = {dx * invtemp, dy * invtemp, dz * invtemp, dw * invtemp};
#pragma unroll
        for (int k = 0; k < 4; ++k) {
            if (j0 + k == row) diag = lg[k];
            float mn = fmaxf(m, lg[k]);
            ssum = ssum * __expf(m - mn) + __expf(lg[k] - mn);
            m = mn;
        }
    }
#pragma unroll
    for (int o = 32; o >= 1; o >>= 1) {
        float m2 = __shfl_xor(m, o);
        float s2 = __shfl_xor(ssum, o);
        float d2 = __shfl_xor(diag, o);
        float mn = fmaxf(m, m2);
        ssum = ssum * __expf(m - mn) + s2 * __expf(m2 - mn);
        m = mn;
        diag += d2;
    }
    if (lane == 0) {
        pm[row * 4 + wv] = m;
        ps[row * 4 + wv] = ssum;
        pd[row * 4 + wv] = diag;
    }
}

__global__ void nce_merge_kernel(const float* __restrict__ pm, const float* __restrict__ ps,
                                 const float* __restrict__ pd, float* __restrict__ acc,
                                 int nrows) {
    int r = blockIdx.x * blockDim.x + threadIdx.x;
    float v = 0.0f;
    if (r < nrows) {
        float m = -1e30f, s = 0.f, d = 0.f;
#pragma unroll
        for (int q = 0; q < 4; ++q) {
            float mq = pm[r * 4 + q], sq = ps[r * 4 + q];
            d += pd[r * 4 + q];
            float mn = fmaxf(m, mq);
            s = s * __expf(m - mn) + sq * __expf(mq - mn);
            m = mn;
        }
        v = m + logf(s) - d;
    }
#pragma unroll
    for (int o = 32; o >= 1; o >>= 1) v += __shfl_xor(v, o);
    if ((threadIdx.x & 63) == 0) unsafeAtomicAdd(acc, v);
}

__global__ void final_kernel(const float* __restrict__ acc, float* __restrict__ out,
                             float invn, float alpha) {
    out[0] = acc[0] * invn + alpha * invn * (acc[1] + acc[2]);
}

// ================================ driver ==================================
// ws proven >= 236 MB (R1 layout ran validated). This layout needs ~183 MB;
// CSR staging overlays the (dead at build time) R2 float region.

extern "C" void kernel_launch(void* const* d_in, const int* in_sizes, int n_in,
                              void* d_out, int out_size, void* d_ws, size_t ws_size,
                              hipStream_t stream) {
    const float* users_feat   = (const float*)d_in[0];
    const float* bundles_feat = (const float*)d_in[1];
    const float* items_feat   = (const float*)d_in[2];
    const float* W1 = (const float*)d_in[3];
    const float* c1 = (const float*)d_in[4];
    const float* W2 = (const float*)d_in[5];
    const float* c2 = (const float*)d_in[6];
    const float* W3 = (const float*)d_in[7];
    const float* c3 = (const float*)d_in[8];
    const float* ui_val = (const float*)d_in[9];
    const float* ub_val = (const float*)d_in[10];
    const float* bi_val = (const float*)d_in[11];
    const int* ui_row = (const int*)d_in[12];
    const int* ui_col = (const int*)d_in[13];
    const int* ub_row = (const int*)d_in[14];
    const int* ub_col = (const int*)d_in[15];
    const int* bi_row = (const int*)d_in[16];
    const int* bi_col = (const int*)d_in[17];
    const int* uidx = (const int*)d_in[18];
    const int* bidx = (const int*)d_in[19];

    const int U  = in_sizes[0] / DD;
    const int NB = in_sizes[1] / DD;
    const int I  = in_sizes[2] / DD;
    const int Eui = in_sizes[9];
    const int Eub = in_sizes[10];
    const int Ebi = in_sizes[11];
    const int BT = in_sizes[18];

    const size_t U64  = (size_t)U * DD;
    const size_t I64  = (size_t)I * DD;
    const size_t NB64 = (size_t)NB * DD;
    const size_t BT64 = (size_t)BT * DD;
    size_t R2sz = 2 * I64; if (R2sz < U64) R2sz = U64;
    if (R2sz < 2 * NB64) R2sz = 2 * NB64;

    // ---------------- float buffers ----------------
    float* w = (float*)d_ws;
    size_t o = 0;
    float* BUF_U = w + o; o += U64;          // x1a -> u1(in-place) -> y1a -> u2(in-place)
    float* R2    = w + o; o += R2sz;         // staging / [x1b|i1] / [b1|b3] / [y1b|b2]
    float* RA    = R2;
    float* RB    = R2 + (R2sz / 2);
    float* u3b = w + o; o += BT64;
    float* u1b = w + o; o += BT64;
    float* u2b = w + o; o += BT64;
    float* b1b = w + o; o += 2 * BT64;
    float* b2b = w + o; o += 2 * BT64;
    float* b3b = w + o; o += 2 * BT64;
    float* A1  = w + o; o += BT64;
    float* A2  = w + o; o += BT64;
    float* B1n = w + o; o += BT64;
    float* B2n = w + o; o += BT64;
    float* pm  = w + o; o += (size_t)BT * 4;
    float* ps  = w + o; o += (size_t)BT * 4;
    float* pd  = w + o; o += (size_t)BT * 4;
    float* acc = w + o; o += 16;

    // ---------------- int area ----------------
    int nmax = U; if (I > nmax) nmax = I; if (NB > nmax) nmax = NB;
    int emax = Eui; if (Eub > emax) emax = Eub; if (Ebi > emax) emax = Ebi;
    int* ib = (int*)(w + o);
    size_t io_ = 0;
    int* cnt  = ib + io_; io_ += (size_t)nmax + 1;   // also per-target cursor
    int* bsum = ib + io_; io_ += 1025;
    int* bcnt = ib + io_; io_ += 1026;
    int* bcur = ib + io_; io_ += 1026;
    int* ptrA = ib + io_; io_ += (size_t)nmax + 1;
    int* ptrB = ib + io_; io_ += (size_t)nmax + 1;
    io_ = (io_ + 3) & ~(size_t)3;                    // 16B align
    int2* pairsA = (int2*)(ib + io_); io_ += (size_t)emax * 2;
    int2* pairsB = (int2*)(ib + io_); io_ += (size_t)emax * 2;

    // NCE transposed operands overlay pairsA (dead after last spmm)
    float* A2t = (float*)pairsA;           // [64][BT]
    float* B2t = A2t + BT64;               // [64][BT]

    auto build = [&](int2* pairs, int* ptr_, const int* tgt, const int* src,
                     const float* val, int n, int E, int* stg) {
        int shift = 0;
        while (((n + (1 << shift) - 1) >> shift) > 1024) ++shift;
        int nbuck = (n + (1 << shift) - 1) >> shift;
        int* stgT = stg;
        int* stgS = stg + (size_t)E;
        float* stgV = (float*)(stg + 2 * (size_t)E);
        int gb = (E + 255) / 256; if (gb > 8192) gb = 8192;
        hipMemsetAsync(bcnt, 0, (nbuck + 1) * sizeof(int), stream);
        bucket_hist_kernel<<<gb, 256, 0, stream>>>(bcnt, tgt, E, shift);
        bucket_scan_kernel<<<1, 1024, 0, stream>>>(bcur, bcnt, nbuck);
        passA_kernel<<<gb, 256, 0, stream>>>(stgT, stgS, stgV, bcur, tgt, src, val, E, shift);
        hipMemsetAsync(cnt, 0, ((size_t)n + 1) * sizeof(int), stream);
        hist_kernel<<<gb, 256, 0, stream>>>(cnt, stgT, E);
        int nb_ = (n + SCAN_EPB - 1) / SCAN_EPB;
        scan_pass1<<<nb_, SCAN_TPB, 0, stream>>>(bsum, cnt, n);
        scan_pass2<<<1, 1024, 0, stream>>>(bsum, nb_, ptr_ + n);
        scan_pass3<<<nb_, SCAN_TPB, 0, stream>>>(ptr_, cnt, cnt, bsum, n);  // cursor=cnt
        passB_kernel<<<gb, 256, 0, stream>>>(pairs, cnt, stgT, stgS, stgV, E);
    };
    auto spmm = [&](float* out_, const float* in_, const int2* pairs, const int* ptr_,
                    int nrows, const float* add1, const float* add2, float scale1,
                    const float* in2, float* out2, const float* addB, float f,
                    float scale2) {
        int blocks = (nrows + 3) / 4;
        spmm_csr_kernel<<<blocks, 256, 0, stream>>>(out_, in_, pairs, ptr_, nrows,
                                                    add1, add2, scale1,
                                                    in2, out2, addB, f, scale2);
    };
    const float k3 = 1.0f / 3.0f;
    const float* NUL = nullptr;

    // ---- View 1 (u-i); u3 == x1a ----
    build(pairsA, ptrA, ui_row, ui_col, ui_val, U, Eui, (int*)R2);  // R2 dead
    spmm(BUF_U, items_feat, pairsA, ptrA, U, NUL, NUL, 1.f, NUL, nullptr, NUL, 0.f, 1.f); // x1a
    gather_rows_kernel<<<(BT * DD + 255) / 256, 256, 0, stream>>>(u3b, BUF_U, uidx, BT, 1);
    build(pairsB, ptrB, ui_col, ui_row, ui_val, I, Eui, (int*)R2);  // R2 still dead
    spmm(RA, users_feat, pairsB, ptrB, I, NUL, NUL, 1.f,
         BUF_U, RB, items_feat, 1.f, k3);                                  // x1b + i1
    spmm(BUF_U, RA, pairsA, ptrA, U, users_feat, BUF_U, k3,
         NUL, nullptr, NUL, 0.f, 1.f);                                     // u1 (in-place)
    gather_rows_norm_kernel<<<BT, 64, 0, stream>>>(u1b, A1, BUF_U, uidx, BT, 1);

    // ---- b1 + b3 (bi graph); staging in dead RA half (x1b), i1 in RB stays live ----
    build(pairsA, ptrA, bi_row, bi_col, bi_val, NB, Ebi, (int*)RA);
    spmm(RA, RB, pairsA, ptrA, NB, NUL, NUL, 1.f,
         items_feat, RA + NB64, NUL, 0.f, 1.f);                            // b1 + b3
    gather_rows_kernel<<<(2 * BT * DD + 255) / 256, 256, 0, stream>>>(b1b, RA, bidx, 2 * BT, 1);
    gather_rows_kernel<<<(2 * BT * DD + 255) / 256, 256, 0, stream>>>(b3b, RA + NB64, bidx, 2 * BT, 1);
    gather_rows_norm_kernel<<<BT, 64, 0, stream>>>(nullptr, B1n, RA, bidx, BT, 2);

    // ---- View 2 (u-b); R2 fully dead again after the b-gathers ----
    build(pairsA, ptrA, ub_row, ub_col, ub_val, U, Eub, (int*)R2);
    spmm(BUF_U, bundles_feat, pairsA, ptrA, U, NUL, NUL, 1.f,
         NUL, nullptr, NUL, 0.f, 1.f);                                     // y1a
    build(pairsB, ptrB, ub_col, ub_row, ub_val, NB, Eub, (int*)R2);
    spmm(RA, users_feat, pairsB, ptrB, NB, NUL, NUL, 1.f,
         BUF_U, RB, bundles_feat, 1.f, k3);                                // y1b + b2
    spmm(BUF_U, RA, pairsA, ptrA, U, users_feat, BUF_U, k3,
         NUL, nullptr, NUL, 0.f, 1.f);                                     // u2 (in-place)
    gather_rows_norm_kernel<<<BT, 64, 0, stream>>>(u2b, A2, BUF_U, uidx, BT, 1);
    gather_rows_kernel<<<(2 * BT * DD + 255) / 256, 256, 0, stream>>>(b2b, RB, bidx, 2 * BT, 1);
    gather_rows_norm_kernel<<<BT, 64, 0, stream>>>(nullptr, B2n, RB, bidx, BT, 2);

    // ---- transposes (into dead pairs area) ----
    transpose64_kernel<<<BT / 64, 256, 0, stream>>>(A2t, A2, BT);
    transpose64_kernel<<<BT / 64, 256, 0, stream>>>(B2t, B2n, BT);

    hipMemsetAsync(acc, 0, 4 * sizeof(float), stream);

    batch_pred_kernel<<<BT, 64, 0, stream>>>(u1b, u2b, u3b, b1b, b2b, b3b,
                                             W1, c1, W2, c2, W3, c3, acc, BT);

    nce_part_kernel<<<BT, 256, 0, stream>>>(A1, A2t, pm, ps, pd, BT, 4.0f);
    nce_merge_kernel<<<(BT + 255) / 256, 256, 0, stream>>>(pm, ps, pd, acc + 1, BT);
    nce_part_kernel<<<BT, 256, 0, stream>>>(B1n, B2t, pm, ps, pd, BT, 4.0f);
    nce_merge_kernel<<<(BT + 255) / 256, 256, 0, stream>>>(pm, ps, pd, acc + 2, BT);

    final_kernel<<<1, 1, 0, stream>>>(acc, (float*)d_out, 1.0f / (float)BT, 0.5f);
}

// Round 8
// 2883.554 us; speedup vs baseline: 3.0481x; 3.0481x over previous
//
#include <hip/hip_runtime.h>
#include <math.h>

#define DD 64
#define SCAN_TPB 256
#define SCAN_EPT 8
#define SCAN_EPB (SCAN_TPB * SCAN_EPT)  // 2048 elements per block
#define NCHUNK 8                         // one target-range chunk per XCD

// ============================ CSR build kernels ============================
// XCD-chunked: block class c = blockIdx.x & 7 handles only targets in chunk c
// (chunk = tgt*8/n). Dispatch round-robins blocks over the 8 XCDs, so each
// chunk's cursor window + pairs write window stays in ONE XCD's L2 -> lines
// fill completely before eviction (write traffic ~= logical bytes).

__global__ void hist_chunked_kernel(int* __restrict__ cnt, const int* __restrict__ tgt,
                                    int E, int n) {
    int myc = blockIdx.x & (NCHUNK - 1);
    int sub = blockIdx.x >> 3;
    int nsub = gridDim.x >> 3;
    int start = sub * blockDim.x + threadIdx.x;
    int stride = nsub * blockDim.x;
    for (int e = start; e < E; e += stride) {
        int t_ = tgt[e];
        int c = (int)(((long long)t_ * NCHUNK) / n);
        if (c == myc) atomicAdd(&cnt[t_], 1);
    }
}

__global__ void scatter_pairs_chunked(int2* __restrict__ pairs, int* __restrict__ cursor,
                                      const int* __restrict__ tgt, const int* __restrict__ src,
                                      const float* __restrict__ val, int E, int n) {
    int myc = blockIdx.x & (NCHUNK - 1);
    int sub = blockIdx.x >> 3;
    int nsub = gridDim.x >> 3;
    int start = sub * blockDim.x + threadIdx.x;
    int stride = nsub * blockDim.x;
    for (int e = start; e < E; e += stride) {
        int t_ = tgt[e];
        int c = (int)(((long long)t_ * NCHUNK) / n);
        if (c == myc) {
            int2 pr;
            pr.x = src[e];
            pr.y = __float_as_int(val[e]);
            int p = atomicAdd(&cursor[t_], 1);
            pairs[p] = pr;
        }
    }
}

__global__ void scan_pass1(int* __restrict__ blocksum, const int* __restrict__ cnt, int n) {
    int base = blockIdx.x * SCAN_EPB + threadIdx.x * SCAN_EPT;
    int s = 0;
#pragma unroll
    for (int k = 0; k < SCAN_EPT; ++k) {
        int i = base + k;
        if (i < n) s += cnt[i];
    }
#pragma unroll
    for (int o = 32; o >= 1; o >>= 1) s += __shfl_xor(s, o);
    __shared__ int ws_[4];
    if ((threadIdx.x & 63) == 0) ws_[threadIdx.x >> 6] = s;
    __syncthreads();
    if (threadIdx.x == 0) blocksum[blockIdx.x] = ws_[0] + ws_[1] + ws_[2] + ws_[3];
}

__global__ void scan_pass2(int* __restrict__ blocksum, int nb, int* __restrict__ ptr_n) {
    __shared__ int sh[1024];
    int t = threadIdx.x;
    int v = (t < nb) ? blocksum[t] : 0;
    sh[t] = v;
    __syncthreads();
    for (int o = 1; o < 1024; o <<= 1) {
        int x = (t >= o) ? sh[t - o] : 0;
        __syncthreads();
        sh[t] += x;
        __syncthreads();
    }
    if (t < nb) blocksum[t] = sh[t] - v;  // exclusive
    if (t == nb - 1) ptr_n[0] = sh[t];
}

// ptr[i] = cursor[i] = blockoff + intra-block exclusive scan (cursor may alias cnt)
__global__ void scan_pass3(int* __restrict__ ptr, int* __restrict__ cursor,
                           const int* __restrict__ cnt, const int* __restrict__ blockoff,
                           int n) {
    int base = blockIdx.x * SCAN_EPB + threadIdx.x * SCAN_EPT;
    int vals[SCAN_EPT];
    int s = 0;
#pragma unroll
    for (int k = 0; k < SCAN_EPT; ++k) {
        int i = base + k;
        int c = (i < n) ? cnt[i] : 0;
        vals[k] = s;
        s += c;
    }
    int incl = s;
#pragma unroll
    for (int o = 1; o < 64; o <<= 1) {
        int x = __shfl_up(incl, o);
        if ((threadIdx.x & 63) >= o) incl += x;
    }
    __shared__ int wtot[4];
    if ((threadIdx.x & 63) == 63) wtot[threadIdx.x >> 6] = incl;
    __syncthreads();
    int woff = 0;
    int wv = threadIdx.x >> 6;
    for (int k = 0; k < 4; ++k)
        if (k < wv) woff += wtot[k];
    int texcl = incl - s + woff + blockoff[blockIdx.x];
#pragma unroll
    for (int k = 0; k < SCAN_EPT; ++k) {
        int i = base + k;
        if (i < n) {
            int p = texcl + vals[k];
            ptr[i] = p;
            cursor[i] = p;
        }
    }
}

// ======================= gather-based segmented SpMM =======================
// one wave per output row; lane = dim.
//   acc  = sum_e val_e * in [src_e];   acc2 = sum_e val_e * in2[src_e]
//   out [r] = (acc  + add1[r] + add2[r]) * scale1        (add2 may alias out)
//   out2[r] = (acc2 + f*acc  + addB[r]) * scale2         (dual only)
__global__ void spmm_csr_kernel(float* __restrict__ out, const float* __restrict__ in,
                                const int2* __restrict__ pairs, const int* __restrict__ ptr,
                                int nrows,
                                const float* __restrict__ add1, const float* __restrict__ add2,
                                float scale1,
                                const float* __restrict__ in2, float* __restrict__ out2,
                                const float* __restrict__ addB, float f, float scale2) {
    int w = (int)(((unsigned)blockIdx.x * blockDim.x + threadIdx.x) >> 6);
    int lane = threadIdx.x & 63;
    if (w >= nrows) return;
    int p = ptr[w];
    int end = ptr[w + 1];
    size_t rowoff = (size_t)w * DD + lane;
    float acc = 0.f, acc2 = 0.f;
    const bool dual = (in2 != nullptr);
    for (; p + 8 <= end; p += 8) {
        int ss[8];
        float vv[8];
#pragma unroll
        for (int k = 0; k < 8; ++k) {
            int2 pr = pairs[p + k];
            ss[k] = __builtin_amdgcn_readfirstlane(pr.x);
            vv[k] = __int_as_float(__builtin_amdgcn_readfirstlane(pr.y));
        }
#pragma unroll
        for (int k = 0; k < 8; ++k) acc += vv[k] * in[(size_t)ss[k] * DD + lane];
        if (dual) {
#pragma unroll
            for (int k = 0; k < 8; ++k) acc2 += vv[k] * in2[(size_t)ss[k] * DD + lane];
        }
    }
    for (; p < end; ++p) {
        int2 pr = pairs[p];
        int s = __builtin_amdgcn_readfirstlane(pr.x);
        float v = __int_as_float(__builtin_amdgcn_readfirstlane(pr.y));
        acc += v * in[(size_t)s * DD + lane];
        if (dual) acc2 += v * in2[(size_t)s * DD + lane];
    }
    float r = acc;
    if (add1) r += add1[rowoff];
    if (add2) r += add2[rowoff];
    out[rowoff] = r * scale1;
    if (dual) {
        float r2 = acc2 + f * acc;
        if (addB) r2 += addB[rowoff];
        out2[rowoff] = r2 * scale2;
    }
}

// ============================= dense helpers ==============================

__global__ void gather_rows_kernel(float* __restrict__ raw, const float* __restrict__ src,
                                   const int* __restrict__ idx, int nrows, int istride) {
    int g = blockIdx.x * blockDim.x + threadIdx.x;
    if (g >= nrows * DD) return;
    int r = g >> 6;
    raw[g] = src[(size_t)idx[(size_t)r * istride] * DD + (g & 63)];
}

__global__ void gather_rows_norm_kernel(float* __restrict__ raw, float* __restrict__ nrm,
                                        const float* __restrict__ src,
                                        const int* __restrict__ idx, int nrows, int istride) {
    int r = blockIdx.x;
    if (r >= nrows) return;
    int d = threadIdx.x;
    float v = src[(size_t)idx[(size_t)r * istride] * DD + d];
    if (raw) raw[(size_t)r * DD + d] = v;
    float ss = v * v;
#pragma unroll
    for (int o = 32; o >= 1; o >>= 1) ss += __shfl_xor(ss, o);
    nrm[(size_t)r * DD + d] = v * rsqrtf(ss + 1e-8f);
}

// out[64][n] = in[n][64]^T
__global__ void transpose64_kernel(float* __restrict__ out, const float* __restrict__ in,
                                   int n) {
    __shared__ float T[64][65];
    int b0 = blockIdx.x * 64;
    int t = threadIdx.x;
#pragma unroll
    for (int k = 0; k < 4; ++k) {
        int f = k * 1024 + t * 4;
        int r = f >> 6, c = f & 63;
        float4 v = *(const float4*)(in + (size_t)(b0 + r) * 64 + c);
        T[r][c] = v.x; T[r][c + 1] = v.y; T[r][c + 2] = v.z; T[r][c + 3] = v.w;
    }
    __syncthreads();
#pragma unroll
    for (int k = 0; k < 4; ++k) {
        int f = k * 1024 + t * 4;
        int d = f >> 6, c = f & 63;
        float4 v;
        v.x = T[c][d]; v.y = T[c + 1][d]; v.z = T[c + 2][d]; v.w = T[c + 3][d];
        *(float4*)(out + (size_t)d * n + b0 + c) = v;
    }
}

__global__ void batch_pred_kernel(const float* __restrict__ u1b, const float* __restrict__ u2b,
                                  const float* __restrict__ u3b,
                                  const float* __restrict__ b1b, const float* __restrict__ b2b,
                                  const float* __restrict__ b3b,
                                  const float* __restrict__ W1, const float* __restrict__ c1,
                                  const float* __restrict__ W2, const float* __restrict__ c2,
                                  const float* __restrict__ W3, const float* __restrict__ c3,
                                  float* __restrict__ acc, int nb) {
    int b = blockIdx.x;
    if (b >= nb) return;
    int d = threadIdx.x;
    float ud1 = u1b[(size_t)b * DD + d];
    float ud2 = u2b[(size_t)b * DD + d];
    float ud3 = u3b[(size_t)b * DD + d];
    float pred[2];
#pragma unroll
    for (int p = 0; p < 2; ++p) {
        size_t r = (size_t)(b * 2 + p) * DD + d;
        float s0 = ud1 * b1b[r];
        float s1 = ud2 * b2b[r];
        float s2 = ud3 * b3b[r];
#pragma unroll
        for (int o = 32; o >= 1; o >>= 1) {
            s0 += __shfl_xor(s0, o);
            s1 += __shfl_xor(s1, o);
            s2 += __shfl_xor(s2, o);
        }
        float t0 = tanhf(s0 * W1[0] + s1 * W1[1] + s2 * W1[2] + c1[0]);
        float t1 = tanhf(s0 * W1[3] + s1 * W1[4] + s2 * W1[5] + c1[1]);
        float t2 = tanhf(s0 * W1[6] + s1 * W1[7] + s2 * W1[8] + c1[2]);
        float g0 = tanhf(t0 * W2[0] + t1 * W2[1] + t2 * W2[2] + c2[0]);
        float g1 = tanhf(t0 * W2[3] + t1 * W2[4] + t2 * W2[5] + c2[1]);
        float g2 = tanhf(t0 * W2[6] + t1 * W2[7] + t2 * W2[8] + c2[2]);
        pred[p] = g0 * W3[0] + g1 * W3[1] + g2 * W3[2] + c3[0];
    }
    if (d == 0) {
        float x = pred[1] - pred[0];
        float sp = (x > 20.0f) ? x : log1pf(expf(x));
        unsafeAtomicAdd(acc, sp);
    }
}

// partial online-LSE: block = 1 row, wave wv handles column quarter wv.
// Bt d-major [64][n], float4 per lane (coalesced 1KB wave loads).
__global__ void nce_part_kernel(const float* __restrict__ A, const float* __restrict__ Bt,
                                float* __restrict__ pm, float* __restrict__ ps,
                                float* __restrict__ pd, int n, float invtemp) {
    int wv = threadIdx.x >> 6;
    int lane = threadIdx.x & 63;
    int row = blockIdx.x;
    float4 a4[16];
    const float4* Ap = (const float4*)(A + (size_t)row * DD);
#pragma unroll
    for (int q = 0; q < 16; ++q) a4[q] = Ap[q];
    int quarter = n >> 2;
    int c0 = wv * quarter;
    float m = -1e30f, ssum = 0.0f, diag = 0.0f;
    int ntile = quarter >> 8;  // tiles of 256 cols
    for (int t = 0; t < ntile; ++t) {
        int j0 = c0 + (t << 8) + (lane << 2);
        float dx = 0.f, dy = 0.f, dz = 0.f, dw = 0.f;
#pragma unroll
        for (int q = 0; q < 16; ++q) {
            float4 a = a4[q];
            float4 r0 = *(const float4*)(Bt + (size_t)(4 * q + 0) * n + j0);
            float4 r1 = *(const float4*)(Bt + (size_t)(4 * q + 1) * n + j0);
            float4 r2 = *(const float4*)(Bt + (size_t)(4 * q + 2) * n + j0);
            float4 r3 = *(const float4*)(Bt + (size_t)(4 * q + 3) * n + j0);
            dx += a.x * r0.x + a.y * r1.x + a.z * r2.x + a.w * r3.x;
            dy += a.x * r0.y + a.y * r1.y + a.z * r2.y + a.w * r3.y;
            dz += a.x * r0.z + a.y * r1.z + a.z * r2.z + a.w * r3.z;
            dw += a.x * r0.w + a.y * r1.w + a.z * r2.w + a.w * r3.w;
        }
        float lg[4] = {dx * invtemp, dy * invtemp, dz * invtemp, dw * invtemp};
#pragma unroll
        for (int k = 0; k < 4; ++k) {
            if (j0 + k == row) diag = lg[k];
            float mn = fmaxf(m, lg[k]);
            ssum = ssum * __expf(m - mn) + __expf(lg[k] - mn);
            m = mn;
        }
    }
#pragma unroll
    for (int o = 32; o >= 1; o >>= 1) {
        float m2 = __shfl_xor(m, o);
        float s2 = __shfl_xor(ssum, o);
        float d2 = __shfl_xor(diag, o);
        float mn = fmaxf(m, m2);
        ssum = ssum * __expf(m - mn) + s2 * __expf(m2 - mn);
        m = mn;
        diag += d2;
    }
    if (lane == 0) {
        pm[row * 4 + wv] = m;
        ps[row * 4 + wv] = ssum;
        pd[row * 4 + wv] = diag;
    }
}

__global__ void nce_merge_kernel(const float* __restrict__ pm, const float* __restrict__ ps,
                                 const float* __restrict__ pd, float* __restrict__ acc,
                                 int nrows) {
    int r = blockIdx.x * blockDim.x + threadIdx.x;
    float v = 0.0f;
    if (r < nrows) {
        float m = -1e30f, s = 0.f, d = 0.f;
#pragma unroll
        for (int q = 0; q < 4; ++q) {
            float mq = pm[r * 4 + q], sq = ps[r * 4 + q];
            d += pd[r * 4 + q];
            float mn = fmaxf(m, mq);
            s = s * __expf(m - mn) + sq * __expf(mq - mn);
            m = mn;
        }
        v = m + logf(s) - d;
    }
#pragma unroll
    for (int o = 32; o >= 1; o >>= 1) v += __shfl_xor(v, o);
    if ((threadIdx.x & 63) == 0) unsafeAtomicAdd(acc, v);
}

__global__ void final_kernel(const float* __restrict__ acc, float* __restrict__ out,
                             float invn, float alpha) {
    out[0] = acc[0] * invn + alpha * invn * (acc[1] + acc[2]);
}

// ================================ driver ==================================
// ws proven >= 235.7 MB (R1 layout ran validated). This layout needs ~185 MB.

extern "C" void kernel_launch(void* const* d_in, const int* in_sizes, int n_in,
                              void* d_out, int out_size, void* d_ws, size_t ws_size,
                              hipStream_t stream) {
    const float* users_feat   = (const float*)d_in[0];
    const float* bundles_feat = (const float*)d_in[1];
    const float* items_feat   = (const float*)d_in[2];
    const float* W1 = (const float*)d_in[3];
    const float* c1 = (const float*)d_in[4];
    const float* W2 = (const float*)d_in[5];
    const float* c2 = (const float*)d_in[6];
    const float* W3 = (const float*)d_in[7];
    const float* c3 = (const float*)d_in[8];
    const float* ui_val = (const float*)d_in[9];
    const float* ub_val = (const float*)d_in[10];
    const float* bi_val = (const float*)d_in[11];
    const int* ui_row = (const int*)d_in[12];
    const int* ui_col = (const int*)d_in[13];
    const int* ub_row = (const int*)d_in[14];
    const int* ub_col = (const int*)d_in[15];
    const int* bi_row = (const int*)d_in[16];
    const int* bi_col = (const int*)d_in[17];
    const int* uidx = (const int*)d_in[18];
    const int* bidx = (const int*)d_in[19];

    const int U  = in_sizes[0] / DD;
    const int NB = in_sizes[1] / DD;
    const int I  = in_sizes[2] / DD;
    const int Eui = in_sizes[9];
    const int Eub = in_sizes[10];
    const int Ebi = in_sizes[11];
    const int BT = in_sizes[18];

    const size_t U64  = (size_t)U * DD;
    const size_t I64  = (size_t)I * DD;
    const size_t NB64 = (size_t)NB * DD;
    const size_t BT64 = (size_t)BT * DD;
    size_t R2sz = 2 * I64; if (R2sz < U64) R2sz = U64;
    if (R2sz < 2 * NB64) R2sz = 2 * NB64;

    // ---------------- float buffers ----------------
    float* w = (float*)d_ws;
    size_t o = 0;
    float* BUF_U = w + o; o += U64;          // x1a -> u1(in-place) -> y1a -> u2(in-place)
    float* R2    = w + o; o += R2sz;         // [x1b|i1] -> [b1|b3] -> [y1b|b2]
    float* RA    = R2;
    float* RB    = R2 + (R2sz / 2);
    float* u3b = w + o; o += BT64;
    float* u1b = w + o; o += BT64;
    float* u2b = w + o; o += BT64;
    float* b1b = w + o; o += 2 * BT64;
    float* b2b = w + o; o += 2 * BT64;
    float* b3b = w + o; o += 2 * BT64;
    float* A1  = w + o; o += BT64;
    float* A2  = w + o; o += BT64;
    float* B1n = w + o; o += BT64;
    float* B2n = w + o; o += BT64;
    float* pm  = w + o; o += (size_t)BT * 4;
    float* ps  = w + o; o += (size_t)BT * 4;
    float* pd  = w + o; o += (size_t)BT * 4;
    float* acc = w + o; o += 16;

    // ---------------- int area ----------------
    int nmax = U; if (I > nmax) nmax = I; if (NB > nmax) nmax = NB;
    int emax = Eui; if (Eub > emax) emax = Eub; if (Ebi > emax) emax = Ebi;
    int* ib = (int*)(w + o);
    size_t io_ = 0;
    int* cnt  = ib + io_; io_ += (size_t)nmax + 1;   // also per-target cursor
    int* bsum = ib + io_; io_ += 1025;
    int* ptrA = ib + io_; io_ += (size_t)nmax + 1;
    int* ptrB = ib + io_; io_ += (size_t)nmax + 1;
    io_ = (io_ + 3) & ~(size_t)3;                    // 16B align
    int2* pairsA = (int2*)(ib + io_); io_ += (size_t)emax * 2;
    int2* pairsB = (int2*)(ib + io_); io_ += (size_t)emax * 2;

    // NCE transposed operands overlay pairsA (dead after last spmm)
    float* A2t = (float*)pairsA;           // [64][BT]
    float* B2t = A2t + BT64;               // [64][BT]

    auto build = [&](int2* pairs, int* ptr_, const int* tgt, const int* src,
                     const float* val, int n, int E) {
        hipMemsetAsync(cnt, 0, ((size_t)n + 1) * sizeof(int), stream);
        hist_chunked_kernel<<<8192, 256, 0, stream>>>(cnt, tgt, E, n);
        int nb_ = (n + SCAN_EPB - 1) / SCAN_EPB;
        scan_pass1<<<nb_, SCAN_TPB, 0, stream>>>(bsum, cnt, n);
        scan_pass2<<<1, 1024, 0, stream>>>(bsum, nb_, ptr_ + n);
        scan_pass3<<<nb_, SCAN_TPB, 0, stream>>>(ptr_, cnt, cnt, bsum, n);  // cursor=cnt
        scatter_pairs_chunked<<<8192, 256, 0, stream>>>(pairs, cnt, tgt, src, val, E, n);
    };
    auto spmm = [&](float* out_, const float* in_, const int2* pairs, const int* ptr_,
                    int nrows, const float* add1, const float* add2, float scale1,
                    const float* in2, float* out2, const float* addB, float f,
                    float scale2) {
        int blocks = (nrows + 3) / 4;
        spmm_csr_kernel<<<blocks, 256, 0, stream>>>(out_, in_, pairs, ptr_, nrows,
                                                    add1, add2, scale1,
                                                    in2, out2, addB, f, scale2);
    };
    const float k3 = 1.0f / 3.0f;
    const float* NUL = nullptr;

    // ---- View 1 (u-i); u3 == x1a ----
    build(pairsA, ptrA, ui_row, ui_col, ui_val, U, Eui);
    spmm(BUF_U, items_feat, pairsA, ptrA, U, NUL, NUL, 1.f, NUL, nullptr, NUL, 0.f, 1.f); // x1a
    gather_rows_kernel<<<(BT * DD + 255) / 256, 256, 0, stream>>>(u3b, BUF_U, uidx, BT, 1);
    build(pairsB, ptrB, ui_col, ui_row, ui_val, I, Eui);
    spmm(RA, users_feat, pairsB, ptrB, I, NUL, NUL, 1.f,
         BUF_U, RB, items_feat, 1.f, k3);                                  // x1b + i1
    spmm(BUF_U, RA, pairsA, ptrA, U, users_feat, BUF_U, k3,
         NUL, nullptr, NUL, 0.f, 1.f);                                     // u1 (in-place)
    gather_rows_norm_kernel<<<BT, 64, 0, stream>>>(u1b, A1, BUF_U, uidx, BT, 1);

    // ---- b1 + b3 (bi graph); i1 lives in RB, outputs go to RA half ----
    build(pairsA, ptrA, bi_row, bi_col, bi_val, NB, Ebi);
    spmm(RA, RB, pairsA, ptrA, NB, NUL, NUL, 1.f,
         items_feat, RA + NB64, NUL, 0.f, 1.f);                            // b1 + b3
    gather_rows_kernel<<<(2 * BT * DD + 255) / 256, 256, 0, stream>>>(b1b, RA, bidx, 2 * BT, 1);
    gather_rows_kernel<<<(2 * BT * DD + 255) / 256, 256, 0, stream>>>(b3b, RA + NB64, bidx, 2 * BT, 1);
    gather_rows_norm_kernel<<<BT, 64, 0, stream>>>(nullptr, B1n, RA, bidx, BT, 2);

    // ---- View 2 (u-b) ----
    build(pairsA, ptrA, ub_row, ub_col, ub_val, U, Eub);
    spmm(BUF_U, bundles_feat, pairsA, ptrA, U, NUL, NUL, 1.f,
         NUL, nullptr, NUL, 0.f, 1.f);                                     // y1a
    build(pairsB, ptrB, ub_col, ub_row, ub_val, NB, Eub);
    spmm(RA, users_feat, pairsB, ptrB, NB, NUL, NUL, 1.f,
         BUF_U, RB, bundles_feat, 1.f, k3);                                // y1b + b2
    spmm(BUF_U, RA, pairsA, ptrA, U, users_feat, BUF_U, k3,
         NUL, nullptr, NUL, 0.f, 1.f);                                     // u2 (in-place)
    gather_rows_norm_kernel<<<BT, 64, 0, stream>>>(u2b, A2, BUF_U, uidx, BT, 1);
    gather_rows_kernel<<<(2 * BT * DD + 255) / 256, 256, 0, stream>>>(b2b, RB, bidx, 2 * BT, 1);
    gather_rows_norm_kernel<<<BT, 64, 0, stream>>>(nullptr, B2n, RB, bidx, BT, 2);

    // ---- transposes (into dead pairs area) ----
    transpose64_kernel<<<BT / 64, 256, 0, stream>>>(A2t, A2, BT);
    transpose64_kernel<<<BT / 64, 256, 0, stream>>>(B2t, B2n, BT);

    hipMemsetAsync(acc, 0, 4 * sizeof(float), stream);

    batch_pred_kernel<<<BT, 64, 0, stream>>>(u1b, u2b, u3b, b1b, b2b, b3b,
                                             W1, c1, W2, c2, W3, c3, acc, BT);

    nce_part_kernel<<<BT, 256, 0, stream>>>(A1, A2t, pm, ps, pd, BT, 4.0f);
    nce_merge_kernel<<<(BT + 255) / 256, 256, 0, stream>>>(pm, ps, pd, acc + 1, BT);
    nce_part_kernel<<<BT, 256, 0, stream>>>(B1n, B2t, pm, ps, pd, BT, 4.0f);
    nce_merge_kernel<<<(BT + 255) / 256, 256, 0, stream>>>(pm, ps, pd, acc + 2, BT);

    final_kernel<<<1, 1, 0, stream>>>(acc, (float*)d_out, 1.0f / (float)BT, 0.5f);
}

// Round 9
// 2297.612 us; speedup vs baseline: 3.8254x; 1.2550x over previous
//
#include <hip/hip_runtime.h>
#include <math.h>

#define DD 64
#define SCAN_TPB 256
#define SCAN_EPT 8
#define SCAN_EPB (SCAN_TPB * SCAN_EPT)  // 2048 elements per block
#define NCHUNK 8                         // one target-range chunk per XCD

// ============================ CSR build kernels ============================
// XCD-chunked full builds (R8, proven): block class c = blockIdx.x & 7 handles
// only targets in chunk c -> cursor + pairs write windows stay in one XCD L2.

__global__ void hist_chunked_kernel(int* __restrict__ cnt, const int* __restrict__ tgt,
                                    int E, int n) {
    int myc = blockIdx.x & (NCHUNK - 1);
    int sub = blockIdx.x >> 3;
    int nsub = gridDim.x >> 3;
    int start = sub * blockDim.x + threadIdx.x;
    int stride = nsub * blockDim.x;
    for (int e = start; e < E; e += stride) {
        int t_ = tgt[e];
        int c = (int)(((long long)t_ * NCHUNK) / n);
        if (c == myc) atomicAdd(&cnt[t_], 1);
    }
}

__global__ void scatter_pairs_chunked(int2* __restrict__ pairs, int* __restrict__ cursor,
                                      const int* __restrict__ tgt, const int* __restrict__ src,
                                      const float* __restrict__ val, int E, int n) {
    int myc = blockIdx.x & (NCHUNK - 1);
    int sub = blockIdx.x >> 3;
    int nsub = gridDim.x >> 3;
    int start = sub * blockDim.x + threadIdx.x;
    int stride = nsub * blockDim.x;
    for (int e = start; e < E; e += stride) {
        int t_ = tgt[e];
        int c = (int)(((long long)t_ * NCHUNK) / n);
        if (c == myc) {
            int2 pr;
            pr.x = src[e];
            pr.y = __float_as_int(val[e]);
            int p = atomicAdd(&cursor[t_], 1);
            pairs[p] = pr;
        }
    }
}

// ---- mini-CSR (batch-marked targets only) ----
__global__ void mark_kernel(int* __restrict__ mark, const int* __restrict__ idx, int n) {
    int g = blockIdx.x * blockDim.x + threadIdx.x;
    if (g < n) mark[idx[g]] = 1;
}

__global__ void hist_marked_kernel(int* __restrict__ cnt, const int* __restrict__ tgt,
                                   const int* __restrict__ mark, int E) {
    int g = blockIdx.x * blockDim.x + threadIdx.x;
    int stride = gridDim.x * blockDim.x;
    for (int e = g; e < E; e += stride) {
        int t_ = tgt[e];
        if (mark[t_]) atomicAdd(&cnt[t_], 1);
    }
}

__global__ void scatter_marked_kernel(int2* __restrict__ pairs, int* __restrict__ cursor,
                                      const int* __restrict__ tgt, const int* __restrict__ src,
                                      const float* __restrict__ val,
                                      const int* __restrict__ mark, int E) {
    int g = blockIdx.x * blockDim.x + threadIdx.x;
    int stride = gridDim.x * blockDim.x;
    for (int e = g; e < E; e += stride) {
        int t_ = tgt[e];
        if (mark[t_]) {
            int2 pr;
            pr.x = src[e];
            pr.y = __float_as_int(val[e]);
            int p = atomicAdd(&cursor[t_], 1);
            pairs[p] = pr;
        }
    }
}

__global__ void scan_pass1(int* __restrict__ blocksum, const int* __restrict__ cnt, int n) {
    int base = blockIdx.x * SCAN_EPB + threadIdx.x * SCAN_EPT;
    int s = 0;
#pragma unroll
    for (int k = 0; k < SCAN_EPT; ++k) {
        int i = base + k;
        if (i < n) s += cnt[i];
    }
#pragma unroll
    for (int o = 32; o >= 1; o >>= 1) s += __shfl_xor(s, o);
    __shared__ int ws_[4];
    if ((threadIdx.x & 63) == 0) ws_[threadIdx.x >> 6] = s;
    __syncthreads();
    if (threadIdx.x == 0) blocksum[blockIdx.x] = ws_[0] + ws_[1] + ws_[2] + ws_[3];
}

__global__ void scan_pass2(int* __restrict__ blocksum, int nb, int* __restrict__ ptr_n) {
    __shared__ int sh[1024];
    int t = threadIdx.x;
    int v = (t < nb) ? blocksum[t] : 0;
    sh[t] = v;
    __syncthreads();
    for (int o = 1; o < 1024; o <<= 1) {
        int x = (t >= o) ? sh[t - o] : 0;
        __syncthreads();
        sh[t] += x;
        __syncthreads();
    }
    if (t < nb) blocksum[t] = sh[t] - v;  // exclusive
    if (t == nb - 1) ptr_n[0] = sh[t];
}

// ptr[i] = cursor[i] = blockoff + intra-block exclusive scan (cursor may alias cnt)
__global__ void scan_pass3(int* __restrict__ ptr, int* __restrict__ cursor,
                           const int* __restrict__ cnt, const int* __restrict__ blockoff,
                           int n) {
    int base = blockIdx.x * SCAN_EPB + threadIdx.x * SCAN_EPT;
    int vals[SCAN_EPT];
    int s = 0;
#pragma unroll
    for (int k = 0; k < SCAN_EPT; ++k) {
        int i = base + k;
        int c = (i < n) ? cnt[i] : 0;
        vals[k] = s;
        s += c;
    }
    int incl = s;
#pragma unroll
    for (int o = 1; o < 64; o <<= 1) {
        int x = __shfl_up(incl, o);
        if ((threadIdx.x & 63) >= o) incl += x;
    }
    __shared__ int wtot[4];
    if ((threadIdx.x & 63) == 63) wtot[threadIdx.x >> 6] = incl;
    __syncthreads();
    int woff = 0;
    int wv = threadIdx.x >> 6;
    for (int k = 0; k < 4; ++k)
        if (k < wv) woff += wtot[k];
    int texcl = incl - s + woff + blockoff[blockIdx.x];
#pragma unroll
    for (int k = 0; k < SCAN_EPT; ++k) {
        int i = base + k;
        if (i < n) {
            int p = texcl + vals[k];
            ptr[i] = p;
            cursor[i] = p;
        }
    }
}

// ======================= gather-based segmented SpMM =======================
// one wave per OUTPUT row w; CSR row r = rowidx ? rowidx[w] : w.
//   acc  = sum_e val_e * in [src_e];   acc2 = sum_e val_e * in2[src_e]
//   out [w] = (acc  + add1[r] + add2[r]) * scale1
//   out2[w] = (acc2 + f*acc  + addB[r]) * scale2     (dual only)
__global__ void spmm_csr_kernel(float* __restrict__ out, const float* __restrict__ in,
                                const int2* __restrict__ pairs, const int* __restrict__ ptr,
                                int nrows, const int* __restrict__ rowidx,
                                const float* __restrict__ add1, const float* __restrict__ add2,
                                float scale1,
                                const float* __restrict__ in2, float* __restrict__ out2,
                                const float* __restrict__ addB, float f, float scale2) {
    int w = (int)(((unsigned)blockIdx.x * blockDim.x + threadIdx.x) >> 6);
    int lane = threadIdx.x & 63;
    if (w >= nrows) return;
    int r = rowidx ? rowidx[w] : w;
    int p = ptr[r];
    int end = ptr[r + 1];
    size_t outoff = (size_t)w * DD + lane;
    size_t nodeoff = (size_t)r * DD + lane;
    float acc = 0.f, acc2 = 0.f;
    const bool dual = (in2 != nullptr);
    for (; p + 8 <= end; p += 8) {
        int ss[8];
        float vv[8];
#pragma unroll
        for (int k = 0; k < 8; ++k) {
            int2 pr = pairs[p + k];
            ss[k] = __builtin_amdgcn_readfirstlane(pr.x);
            vv[k] = __int_as_float(__builtin_amdgcn_readfirstlane(pr.y));
        }
#pragma unroll
        for (int k = 0; k < 8; ++k) acc += vv[k] * in[(size_t)ss[k] * DD + lane];
        if (dual) {
#pragma unroll
            for (int k = 0; k < 8; ++k) acc2 += vv[k] * in2[(size_t)ss[k] * DD + lane];
        }
    }
    for (; p < end; ++p) {
        int2 pr = pairs[p];
        int s = __builtin_amdgcn_readfirstlane(pr.x);
        float v = __int_as_float(__builtin_amdgcn_readfirstlane(pr.y));
        acc += v * in[(size_t)s * DD + lane];
        if (dual) acc2 += v * in2[(size_t)s * DD + lane];
    }
    float rr = acc;
    if (add1) rr += add1[nodeoff];
    if (add2) rr += add2[nodeoff];
    out[outoff] = rr * scale1;
    if (dual) {
        float r2 = acc2 + f * acc;
        if (addB) r2 += addB[nodeoff];
        out2[outoff] = r2 * scale2;
    }
}

// ============================= dense helpers ==============================

__global__ void gather_rows_kernel(float* __restrict__ raw, const float* __restrict__ src,
                                   const int* __restrict__ idx, int nrows) {
    int g = blockIdx.x * blockDim.x + threadIdx.x;
    if (g >= nrows * DD) return;
    int r = g >> 6;
    raw[g] = src[(size_t)idx[r] * DD + (g & 63)];
}

// nrm[r] = normalize(src[r*rstride])   (1 wave/row, rows already batch-ordered)
__global__ void norm_rows_kernel(float* __restrict__ nrm, const float* __restrict__ src,
                                 int nrows, int rstride) {
    int r = blockIdx.x;
    if (r >= nrows) return;
    int d = threadIdx.x;
    float v = src[(size_t)r * rstride * DD + d];
    float ss = v * v;
#pragma unroll
    for (int o = 32; o >= 1; o >>= 1) ss += __shfl_xor(ss, o);
    nrm[(size_t)r * DD + d] = v * rsqrtf(ss + 1e-8f);
}

// out[64][n] = in[n][64]^T
__global__ void transpose64_kernel(float* __restrict__ out, const float* __restrict__ in,
                                   int n) {
    __shared__ float T[64][65];
    int b0 = blockIdx.x * 64;
    int t = threadIdx.x;
#pragma unroll
    for (int k = 0; k < 4; ++k) {
        int f = k * 1024 + t * 4;
        int r = f >> 6, c = f & 63;
        float4 v = *(const float4*)(in + (size_t)(b0 + r) * 64 + c);
        T[r][c] = v.x; T[r][c + 1] = v.y; T[r][c + 2] = v.z; T[r][c + 3] = v.w;
    }
    __syncthreads();
#pragma unroll
    for (int k = 0; k < 4; ++k) {
        int f = k * 1024 + t * 4;
        int d = f >> 6, c = f & 63;
        float4 v;
        v.x = T[c][d]; v.y = T[c + 1][d]; v.z = T[c + 2][d]; v.w = T[c + 3][d];
        *(float4*)(out + (size_t)d * n + b0 + c) = v;
    }
}

__global__ void batch_pred_kernel(const float* __restrict__ u1b, const float* __restrict__ u2b,
                                  const float* __restrict__ u3b,
                                  const float* __restrict__ b1b, const float* __restrict__ b2b,
                                  const float* __restrict__ b3b,
                                  const float* __restrict__ W1, const float* __restrict__ c1,
                                  const float* __restrict__ W2, const float* __restrict__ c2,
                                  const float* __restrict__ W3, const float* __restrict__ c3,
                                  float* __restrict__ acc, int nb) {
    int b = blockIdx.x;
    if (b >= nb) return;
    int d = threadIdx.x;
    float ud1 = u1b[(size_t)b * DD + d];
    float ud2 = u2b[(size_t)b * DD + d];
    float ud3 = u3b[(size_t)b * DD + d];
    float pred[2];
#pragma unroll
    for (int p = 0; p < 2; ++p) {
        size_t r = (size_t)(b * 2 + p) * DD + d;
        float s0 = ud1 * b1b[r];
        float s1 = ud2 * b2b[r];
        float s2 = ud3 * b3b[r];
#pragma unroll
        for (int o = 32; o >= 1; o >>= 1) {
            s0 += __shfl_xor(s0, o);
            s1 += __shfl_xor(s1, o);
            s2 += __shfl_xor(s2, o);
        }
        float t0 = tanhf(s0 * W1[0] + s1 * W1[1] + s2 * W1[2] + c1[0]);
        float t1 = tanhf(s0 * W1[3] + s1 * W1[4] + s2 * W1[5] + c1[1]);
        float t2 = tanhf(s0 * W1[6] + s1 * W1[7] + s2 * W1[8] + c1[2]);
        float g0 = tanhf(t0 * W2[0] + t1 * W2[1] + t2 * W2[2] + c2[0]);
        float g1 = tanhf(t0 * W2[3] + t1 * W2[4] + t2 * W2[5] + c2[1]);
        float g2 = tanhf(t0 * W2[6] + t1 * W2[7] + t2 * W2[8] + c2[2]);
        pred[p] = g0 * W3[0] + g1 * W3[1] + g2 * W3[2] + c3[0];
    }
    if (d == 0) {
        float x = pred[1] - pred[0];
        float sp = (x > 20.0f) ? x : log1pf(expf(x));
        unsafeAtomicAdd(acc, sp);
    }
}

// partial online-LSE: block = 1 row, wave wv handles column quarter wv.
__global__ void nce_part_kernel(const float* __restrict__ A, const float* __restrict__ Bt,
                                float* __restrict__ pm, float* __restrict__ ps,
                                float* __restrict__ pd, int n, float invtemp) {
    int wv = threadIdx.x >> 6;
    int lane = threadIdx.x & 63;
    int row = blockIdx.x;
    float4 a4[16];
    const float4* Ap = (const float4*)(A + (size_t)row * DD);
#pragma unroll
    for (int q = 0; q < 16; ++q) a4[q] = Ap[q];
    int quarter = n >> 2;
    int c0 = wv * quarter;
    float m = -1e30f, ssum = 0.0f, diag = 0.0f;
    int ntile = quarter >> 8;  // tiles of 256 cols
    for (int t = 0; t < ntile; ++t) {
        int j0 = c0 + (t << 8) + (lane << 2);
        float dx = 0.f, dy = 0.f, dz = 0.f, dw = 0.f;
#pragma unroll
        for (int q = 0; q < 16; ++q) {
            float4 a = a4[q];
            float4 r0 = *(const float4*)(Bt + (size_t)(4 * q + 0) * n + j0);
            float4 r1 = *(const float4*)(Bt + (size_t)(4 * q + 1) * n + j0);
            float4 r2 = *(const float4*)(Bt + (size_t)(4 * q + 2) * n + j0);
            float4 r3 = *(const float4*)(Bt + (size_t)(4 * q + 3) * n + j0);
            dx += a.x * r0.x + a.y * r1.x + a.z * r2.x + a.w * r3.x;
            dy += a.x * r0.y + a.y * r1.y + a.z * r2.y + a.w * r3.y;
            dz += a.x * r0.z + a.y * r1.z + a.z * r2.z + a.w * r3.z;
            dw += a.x * r0.w + a.y * r1.w + a.z * r2.w + a.w * r3.w;
        }
        float lg[4] = {dx * invtemp, dy * invtemp, dz * invtemp, dw * invtemp};
#pragma unroll
        for (int k = 0; k < 4; ++k) {
            if (j0 + k == row) diag = lg[k];
            float mn = fmaxf(m, lg[k]);
            ssum = ssum * __expf(m - mn) + __expf(lg[k] - mn);
            m = mn;
        }
    }
#pragma unroll
    for (int o = 32; o >= 1; o >>= 1) {
        float m2 = __shfl_xor(m, o);
        float s2 = __shfl_xor(ssum, o);
        float d2 = __shfl_xor(diag, o);
        float mn = fmaxf(m, m2);
        ssum = ssum * __expf(m - mn) + s2 * __expf(m2 - mn);
        m = mn;
        diag += d2;
    }
    if (lane == 0) {
        pm[row * 4 + wv] = m;
        ps[row * 4 + wv] = ssum;
        pd[row * 4 + wv] = diag;
    }
}

__global__ void nce_merge_kernel(const float* __restrict__ pm, const float* __restrict__ ps,
                                 const float* __restrict__ pd, float* __restrict__ acc,
                                 int nrows) {
    int r = blockIdx.x * blockDim.x + threadIdx.x;
    float v = 0.0f;
    if (r < nrows) {
        float m = -1e30f, s = 0.f, d = 0.f;
#pragma unroll
        for (int q = 0; q < 4; ++q) {
            float mq = pm[r * 4 + q], sq = ps[r * 4 + q];
            d += pd[r * 4 + q];
            float mn = fmaxf(m, mq);
            s = s * __expf(m - mn) + sq * __expf(mq - mn);
            m = mn;
        }
        v = m + logf(s) - d;
    }
#pragma unroll
    for (int o = 32; o >= 1; o >>= 1) v += __shfl_xor(v, o);
    if ((threadIdx.x & 63) == 0) unsafeAtomicAdd(acc, v);
}

__global__ void final_kernel(const float* __restrict__ acc, float* __restrict__ out,
                             float invn, float alpha) {
    out[0] = acc[0] * invn + alpha * invn * (acc[1] + acc[2]);
}

// ================================ driver ==================================
// ws proven >= 235.7 MB. This layout needs ~183 MB.

extern "C" void kernel_launch(void* const* d_in, const int* in_sizes, int n_in,
                              void* d_out, int out_size, void* d_ws, size_t ws_size,
                              hipStream_t stream) {
    const float* users_feat   = (const float*)d_in[0];
    const float* bundles_feat = (const float*)d_in[1];
    const float* items_feat   = (const float*)d_in[2];
    const float* W1 = (const float*)d_in[3];
    const float* c1 = (const float*)d_in[4];
    const float* W2 = (const float*)d_in[5];
    const float* c2 = (const float*)d_in[6];
    const float* W3 = (const float*)d_in[7];
    const float* c3 = (const float*)d_in[8];
    const float* ui_val = (const float*)d_in[9];
    const float* ub_val = (const float*)d_in[10];
    const float* bi_val = (const float*)d_in[11];
    const int* ui_row = (const int*)d_in[12];
    const int* ui_col = (const int*)d_in[13];
    const int* ub_row = (const int*)d_in[14];
    const int* ub_col = (const int*)d_in[15];
    const int* bi_row = (const int*)d_in[16];
    const int* bi_col = (const int*)d_in[17];
    const int* uidx = (const int*)d_in[18];
    const int* bidx = (const int*)d_in[19];

    const int U  = in_sizes[0] / DD;
    const int NB = in_sizes[1] / DD;
    const int I  = in_sizes[2] / DD;
    const int Eui = in_sizes[9];
    const int Eub = in_sizes[10];
    const int Ebi = in_sizes[11];
    const int BT = in_sizes[18];

    const size_t U64  = (size_t)U * DD;
    const size_t I64  = (size_t)I * DD;
    const size_t BT64 = (size_t)BT * DD;

    // ---------------- float buffers ----------------
    float* w = (float*)d_ws;
    size_t o = 0;
    float* BUF_U = w + o; o += U64;    // x1a -> y1a
    float* RA    = w + o; o += I64;    // x1b -> y1b
    float* RB    = w + o; o += I64;    // i1
    float* u3b = w + o; o += BT64;
    float* u1b = w + o; o += BT64;
    float* u2b = w + o; o += BT64;
    float* b1b = w + o; o += 2 * BT64;
    float* b2b = w + o; o += 2 * BT64;
    float* b3b = w + o; o += 2 * BT64;
    float* A1  = w + o; o += BT64;
    float* A2  = w + o; o += BT64;
    float* B1n = w + o; o += BT64;
    float* B2n = w + o; o += BT64;
    float* pm  = w + o; o += (size_t)BT * 4;
    float* ps  = w + o; o += (size_t)BT * 4;
    float* pd  = w + o; o += (size_t)BT * 4;
    float* acc = w + o; o += 16;

    // ---------------- int area ----------------
    int nmax = U; if (I > nmax) nmax = I; if (NB > nmax) nmax = NB;
    int emax = Eui; if (Eub > emax) emax = Eub; if (Ebi > emax) emax = Ebi;
    int* ib = (int*)(w + o);
    size_t io_ = 0;
    int* cnt  = ib + io_; io_ += (size_t)nmax + 1;   // also cursor
    int* bsum = ib + io_; io_ += 1025;
    int* mark = ib + io_; io_ += (size_t)NB + 1;
    int* ptrA = ib + io_; io_ += (size_t)nmax + 1;
    int* ptrB = ib + io_; io_ += (size_t)nmax + 1;
    io_ = (io_ + 3) & ~(size_t)3;
    int2* pairsA = (int2*)(ib + io_); io_ += (size_t)emax * 2;
    int2* pairsB = (int2*)(ib + io_); io_ += (size_t)emax * 2;

    // NCE transposed operands overlay pairsB tail area? use pairsA (dead last)
    float* A2t = (float*)pairsA;           // [64][BT]
    float* B2t = A2t + BT64;               // [64][BT]

    auto build = [&](int2* pairs, int* ptr_, const int* tgt, const int* src,
                     const float* val, int n, int E) {
        hipMemsetAsync(cnt, 0, ((size_t)n + 1) * sizeof(int), stream);
        hist_chunked_kernel<<<8192, 256, 0, stream>>>(cnt, tgt, E, n);
        int nb_ = (n + SCAN_EPB - 1) / SCAN_EPB;
        scan_pass1<<<nb_, SCAN_TPB, 0, stream>>>(bsum, cnt, n);
        scan_pass2<<<1, 1024, 0, stream>>>(bsum, nb_, ptr_ + n);
        scan_pass3<<<nb_, SCAN_TPB, 0, stream>>>(ptr_, cnt, cnt, bsum, n);  // cursor=cnt
        scatter_pairs_chunked<<<8192, 256, 0, stream>>>(pairs, cnt, tgt, src, val, E, n);
    };
    auto spmm = [&](float* out_, const float* in_, const int2* pairs, const int* ptr_,
                    int nrows, const int* rowidx,
                    const float* add1, const float* add2, float scale1,
                    const float* in2, float* out2, const float* addB, float f,
                    float scale2) {
        int blocks = (nrows + 3) / 4;
        spmm_csr_kernel<<<blocks, 256, 0, stream>>>(out_, in_, pairs, ptr_, nrows, rowidx,
                                                    add1, add2, scale1,
                                                    in2, out2, addB, f, scale2);
    };
    const float k3 = 1.0f / 3.0f;
    const float* NUL = nullptr;
    const int* NULI = nullptr;

    // ---- View 1 (u-i) ----
    build(pairsA, ptrA, ui_row, ui_col, ui_val, U, Eui);
    spmm(BUF_U, items_feat, pairsA, ptrA, U, NULI,
         NUL, NUL, 1.f, NUL, nullptr, NUL, 0.f, 1.f);                      // x1a (full)
    gather_rows_kernel<<<(BT * DD + 255) / 256, 256, 0, stream>>>(u3b, BUF_U, uidx, BT);
    build(pairsB, ptrB, ui_col, ui_row, ui_val, I, Eui);
    spmm(RA, users_feat, pairsB, ptrB, I, NULI,
         NUL, NUL, 1.f,
         BUF_U, RB, items_feat, 1.f, k3);                                  // x1b + i1 (full)
    spmm(u1b, RA, pairsA, ptrA, BT, uidx,
         users_feat, BUF_U, k3, NUL, nullptr, NUL, 0.f, 1.f);              // u1 (batch only)
    norm_rows_kernel<<<BT, 64, 0, stream>>>(A1, u1b, BT, 1);

    // ---- b1 + b3 via mini-CSR over batch-marked bundles ----
    hipMemsetAsync(mark, 0, ((size_t)NB + 1) * sizeof(int), stream);
    mark_kernel<<<(2 * BT + 255) / 256, 256, 0, stream>>>(mark, bidx, 2 * BT);
    hipMemsetAsync(cnt, 0, ((size_t)NB + 1) * sizeof(int), stream);
    {
        int gb = (Ebi + 255) / 256; if (gb > 4096) gb = 4096;
        hist_marked_kernel<<<gb, 256, 0, stream>>>(cnt, bi_row, mark, Ebi);
        int nb_ = (NB + SCAN_EPB - 1) / SCAN_EPB;
        scan_pass1<<<nb_, SCAN_TPB, 0, stream>>>(bsum, cnt, NB);
        scan_pass2<<<1, 1024, 0, stream>>>(bsum, nb_, ptrA + NB);
        scan_pass3<<<nb_, SCAN_TPB, 0, stream>>>(ptrA, cnt, cnt, bsum, NB);
        scatter_marked_kernel<<<gb, 256, 0, stream>>>(pairsA, cnt, bi_row, bi_col,
                                                      bi_val, mark, Ebi);
    }
    spmm(b1b, RB, pairsA, ptrA, 2 * BT, bidx,
         NUL, NUL, 1.f,
         items_feat, b3b, NUL, 0.f, 1.f);                                  // b1b + b3b
    norm_rows_kernel<<<BT, 64, 0, stream>>>(B1n, b1b, BT, 2);

    // ---- View 2 (u-b) ----
    build(pairsA, ptrA, ub_row, ub_col, ub_val, U, Eub);
    spmm(BUF_U, bundles_feat, pairsA, ptrA, U, NULI,
         NUL, NUL, 1.f, NUL, nullptr, NUL, 0.f, 1.f);                      // y1a (full)
    build(pairsB, ptrB, ub_col, ub_row, ub_val, NB, Eub);
    spmm(RA, users_feat, pairsB, ptrB, NB, NULI,
         NUL, NUL, 1.f, NUL, nullptr, NUL, 0.f, 1.f);                      // y1b (full)
    spmm(u2b, RA, pairsA, ptrA, BT, uidx,
         users_feat, BUF_U, k3, NUL, nullptr, NUL, 0.f, 1.f);              // u2 (batch only)
    norm_rows_kernel<<<BT, 64, 0, stream>>>(A2, u2b, BT, 1);
    spmm(b2b, BUF_U, pairsB, ptrB, 2 * BT, bidx,
         bundles_feat, RA, k3, NUL, nullptr, NUL, 0.f, 1.f);               // b2 (batch only)
    norm_rows_kernel<<<BT, 64, 0, stream>>>(B2n, b2b, BT, 2);

    // ---- transposes (into dead pairsA area) ----
    transpose64_kernel<<<BT / 64, 256, 0, stream>>>(A2t, A2, BT);
    transpose64_kernel<<<BT / 64, 256, 0, stream>>>(B2t, B2n, BT);

    hipMemsetAsync(acc, 0, 4 * sizeof(float), stream);

    batch_pred_kernel<<<BT, 64, 0, stream>>>(u1b, u2b, u3b, b1b, b2b, b3b,
                                             W1, c1, W2, c2, W3, c3, acc, BT);

    nce_part_kernel<<<BT, 256, 0, stream>>>(A1, A2t, pm, ps, pd, BT, 4.0f);
    nce_merge_kernel<<<(BT + 255) / 256, 256, 0, stream>>>(pm, ps, pd, acc + 1, BT);
    nce_part_kernel<<<BT, 256, 0, stream>>>(B1n, B2t, pm, ps, pd, BT, 4.0f);
    nce_merge_kernel<<<(BT + 255) / 256, 256, 0, stream>>>(pm, ps, pd, acc + 2, BT);

    final_kernel<<<1, 1, 0, stream>>>(acc, (float*)d_out, 1.0f / (float)BT, 0.5f);
}